// Round 5
// baseline (448.831 us; speedup 1.0000x reference)
//
#include <hip/hip_runtime.h>
#include <hip/hip_fp16.h>
#include <math.h>

#define NN   50000
#define EE   1600000
#define FD   128
#define OUTD 40
#define NEG  0.2f
#define RNG  6250          // NN / 8 (exact)
#define SCAT_BLOCKS 2048   // 256 edge-slices x 8 dst-ranges

__device__ __forceinline__ float lrelu(float v) { return v > 0.f ? v : NEG * v; }

__device__ __forceinline__ int fenc(float f) { int b = __float_as_int(f); return b < 0 ? (b ^ 0x7FFFFFFF) : b; }
__device__ __forceinline__ float fdec(int v) { v = v < 0 ? (v ^ 0x7FFFFFFF) : v; return __int_as_float(v); }

__device__ __forceinline__ int ntl(const int* p) { return __builtin_nontemporal_load(p); }

typedef float nfloat2 __attribute__((ext_vector_type(2)));
typedef float nfloat4 __attribute__((ext_vector_type(4)));

__device__ __forceinline__ nfloat2 ntl2(const void* p) {
  return __builtin_nontemporal_load((const nfloat2*)p);
}
__device__ __forceinline__ nfloat4 ntl4(const void* p) {
  return __builtin_nontemporal_load((const nfloat4*)p);
}

struct alignas(8) half4 { __half2 lo, hi; };

// ---------------- precompute collapsed weights ----------------
__global__ __launch_bounds__(256) void k_precompute(
    const float* __restrict__ Wr0, const float* __restrict__ ar0, const float* __restrict__ br0,
    const float* __restrict__ Wr1, const float* __restrict__ ar1, const float* __restrict__ br1,
    const float* __restrict__ Wm1, const float* __restrict__ bm1,
    const float* __restrict__ Wm2, const float* __restrict__ bm2,
    float* __restrict__ wrv0, float* __restrict__ brd0,
    float* __restrict__ wrv1, float* __restrict__ brd1,
    float* __restrict__ Wp, float* __restrict__ bp, int* __restrict__ mAL)
{
  int gid = blockIdx.x * 256 + threadIdx.x;
  if (gid < 256) {
    int k = gid >> 1, h = gid & 1;
    float s = 0.f;
    for (int c = 0; c < 64; ++c) s += Wr0[k*FD + h*64 + c] * ar0[h*64 + c];
    wrv0[k*2 + h] = s;
  } else if (gid < 512) {
    int idx = gid - 256; int k = idx >> 1, h = idx & 1;
    float s = 0.f;
    for (int c = 0; c < 64; ++c) s += Wr1[k*FD + h*64 + c] * ar1[h*64 + c];
    wrv1[k*2 + h] = s;
  } else if (gid < 512 + FD*OUTD) {
    int idx = gid - 512; int k = idx / OUTD, o = idx % OUTD;
    float s = 0.f;
    for (int j = 0; j < 64; ++j) s += Wm1[k*64 + j] * Wm2[j*OUTD + o];
    Wp[k*OUTD + o] = s;
  } else if (gid < 512 + FD*OUTD + OUTD) {
    int o = gid - (512 + FD*OUTD);
    float s = bm2[o];
    for (int j = 0; j < 64; ++j) s += bm1[j] * Wm2[j*OUTD + o];
    bp[o] = s;
  } else if (gid < 512 + FD*OUTD + OUTD + 4) {
    int idx = gid - (512 + FD*OUTD + OUTD);
    int l = idx >> 1, h = idx & 1;
    const float* br = l ? br1 : br0;
    const float* ar = l ? ar1 : ar0;
    float s = 0.f;
    for (int c = 0; c < 64; ++c) s += br[h*64 + c] * ar[h*64 + c];
    (l ? brd1 : brd0)[h] = s;
  } else if (gid < 512 + FD*OUTD + OUTD + 8) {
    mAL[gid - (512 + FD*OUTD + OUTD + 4)] = 0x80000000;
  }
}

// ---------------- fused GEMM + alpha_l + alpha_r; writes XL as f16 ----------------
__global__ __launch_bounds__(256) void k_gemm_alpha(
    const float* __restrict__ X, const float* __restrict__ Wl, const float* __restrict__ bl,
    const float* __restrict__ al, const float* __restrict__ wrv, const float* __restrict__ brd,
    __half* __restrict__ XLh, float* __restrict__ AL, float* __restrict__ AR)
{
  __shared__ float sW[FD*FD];
  __shared__ float sX[32*FD];
  int t = threadIdx.x;
  int base = blockIdx.x * 32;
  {
    const float4* W4 = (const float4*)Wl;
    float4* sW4 = (float4*)sW;
    #pragma unroll
    for (int i = 0; i < 16; ++i) sW4[t + i*256] = W4[t + i*256];
    int rows = NN - base; if (rows > 32) rows = 32;
    int nf4 = rows * 32;
    const float4* X4 = (const float4*)(X + (size_t)base * FD);
    float4* sX4 = (float4*)sX;
    #pragma unroll
    for (int i = 0; i < 4; ++i) {
      int idx = t + i*256;
      sX4[idx] = (idx < nf4) ? X4[idx] : make_float4(0.f,0.f,0.f,0.f);
    }
  }
  __syncthreads();
  int cg = t & 31, rg = t >> 5;
  int c0 = cg * 4;
  float acc[4][4] = {};
  #pragma unroll 4
  for (int k = 0; k < FD; ++k) {
    float4 wv = *(const float4*)&sW[k*FD + c0];
    #pragma unroll
    for (int r = 0; r < 4; ++r) {
      float xv = sX[(rg*4+r)*FD + k];
      acc[r][0] = fmaf(xv, wv.x, acc[r][0]);
      acc[r][1] = fmaf(xv, wv.y, acc[r][1]);
      acc[r][2] = fmaf(xv, wv.z, acc[r][2]);
      acc[r][3] = fmaf(xv, wv.w, acc[r][3]);
    }
  }
  float4 bias = *(const float4*)&bl[c0];
  int lane = t & 63;
  int head = cg >> 4;
  const float* alh = al + head*64 + (c0 & 63);
  float a0_0 = alh[0], a0_1 = alh[1], a0_2 = alh[2], a0_3 = alh[3];
  #pragma unroll
  for (int r = 0; r < 4; ++r) {
    int row = base + rg*4 + r;
    float4 o;
    o.x = acc[r][0] + bias.x; o.y = acc[r][1] + bias.y;
    o.z = acc[r][2] + bias.z; o.w = acc[r][3] + bias.w;
    if (row < NN) {
      half4 hv; hv.lo = __floats2half2_rn(o.x, o.y); hv.hi = __floats2half2_rn(o.z, o.w);
      *(half4*)&XLh[(size_t)row*FD + c0] = hv;
    }
    float av = o.x*a0_0 + o.y*a0_1 + o.z*a0_2 + o.w*a0_3;
    #pragma unroll
    for (int off = 1; off < 16; off <<= 1) av += __shfl_xor(av, off);
    if ((lane & 15) == 0 && row < NN) AL[(size_t)row*2 + head] = av;
    float p0 = 0.f, p1 = 0.f;
    #pragma unroll
    for (int j = 0; j < 4; ++j) {
      float xv = sX[(rg*4+r)*FD + c0 + j];
      p0 = fmaf(xv, wrv[(c0+j)*2 + 0], p0);
      p1 = fmaf(xv, wrv[(c0+j)*2 + 1], p1);
    }
    #pragma unroll
    for (int off = 1; off < 32; off <<= 1) { p0 += __shfl_xor(p0, off); p1 += __shfl_xor(p1, off); }
    if ((lane & 31) == 0 && row < NN) {
      AR[(size_t)row*2 + 0] = p0 + brd[0];
      AR[(size_t)row*2 + 1] = p1 + brd[1];
    }
  }
}

// ---------------- global max of AL per head ----------------
__global__ __launch_bounds__(256) void k_maxal(const float* __restrict__ AL, int* __restrict__ mAL) {
  float m0 = -INFINITY, m1 = -INFINITY;
  for (int i = blockIdx.x*256 + threadIdx.x; i < NN; i += gridDim.x*256) {
    nfloat2 v = ntl2(&AL[2*i]);
    m0 = fmaxf(m0, v.x); m1 = fmaxf(m1, v.y);
  }
  #pragma unroll
  for (int off = 1; off < 64; off <<= 1) {
    m0 = fmaxf(m0, __shfl_xor(m0, off));
    m1 = fmaxf(m1, __shfl_xor(m1, off));
  }
  if ((threadIdx.x & 63) == 0) {
    atomicMax(&mAL[0], fenc(m0));
    atomicMax(&mAL[1], fenc(m1));
  }
}

// ---------------- CSR build, XCD-partitioned + nt streams ----------------
// block b: dst-range (b&7) -> XCD b%8 (hw round-robin, all blocks co-resident),
// edge slice (b>>3). Atomics + csr writes stay in one XCD's L2; the dst/src
// streams use nontemporal loads so they don't evict those lines.
__global__ __launch_bounds__(256) void k_hist(const int* __restrict__ dst, int* __restrict__ cnt) {
  int r = blockIdx.x & 7;
  int s = blockIdx.x >> 3;
  const int nslice = SCAT_BLOCKS / 8;
  const int chunk = (EE + nslice - 1) / nslice;
  int e0 = s * chunk, e1 = min(e0 + chunk, EE);
  int lo = r * RNG, hi = lo + RNG;
  for (int e = e0 + threadIdx.x; e < e1; e += 256) {
    int d = ntl(&dst[e]);
    if (d >= lo && d < hi) atomicAdd(&cnt[d], 1);
  }
}

__global__ __launch_bounds__(256) void k_scan1(const int* __restrict__ cnt,
                                               int* __restrict__ excl, int* __restrict__ partials) {
  __shared__ int tmp[256];
  int t = threadIdx.x;
  int g = blockIdx.x * 256 + t;
  int v = (g < NN) ? cnt[g] : 0;
  tmp[t] = v;
  __syncthreads();
  #pragma unroll
  for (int off = 1; off < 256; off <<= 1) {
    int u = (t >= off) ? tmp[t - off] : 0;
    __syncthreads();
    tmp[t] += u;
    __syncthreads();
  }
  if (g < NN) excl[g] = tmp[t] - v;
  if (t == 255) partials[blockIdx.x] = tmp[255];
}

__global__ __launch_bounds__(256) void k_scan2(const int* __restrict__ partials, int* __restrict__ poff) {
  __shared__ int tmp[256];
  int t = threadIdx.x;
  const int nb = (NN + 255) / 256;
  int v = (t < nb) ? partials[t] : 0;
  tmp[t] = v;
  __syncthreads();
  #pragma unroll
  for (int off = 1; off < 256; off <<= 1) {
    int u = (t >= off) ? tmp[t - off] : 0;
    __syncthreads();
    tmp[t] += u;
    __syncthreads();
  }
  poff[t] = tmp[t] - v;
}

__global__ __launch_bounds__(256) void k_scan3(int* __restrict__ row_off, const int* __restrict__ poff) {
  int g = blockIdx.x * 256 + threadIdx.x;
  if (g < NN) row_off[g] += poff[blockIdx.x];
  if (g == 0) row_off[NN] = EE;
}

__global__ __launch_bounds__(256) void k_scatter(const int* __restrict__ src, const int* __restrict__ dst,
    const int* __restrict__ row_off, int* __restrict__ cursor, int* __restrict__ csr_src) {
  int r = blockIdx.x & 7;
  int s = blockIdx.x >> 3;
  const int nslice = SCAT_BLOCKS / 8;
  const int chunk = (EE + nslice - 1) / nslice;
  int e0 = s * chunk, e1 = min(e0 + chunk, EE);
  int lo = r * RNG, hi = lo + RNG;
  for (int e = e0 + threadIdx.x; e < e1; e += 256) {
    int d = ntl(&dst[e]);
    if (d >= lo && d < hi) {
      int sv = ntl(&src[e]);
      int pos = row_off[d] + atomicAdd(&cursor[d], 1);
      csr_src[pos] = sv;
    }
  }
}

// ---------------- fused attention + aggregation ----------------
// wave per node; 4 edge-groups x 16 lanes; lane l covers dims [8l, 8l+8) (head = l>>3)
__global__ __launch_bounds__(256) void k_agg(
    const __half* __restrict__ XLh, const float* __restrict__ AL,
    const float* __restrict__ AR, const int* __restrict__ mAL,
    const int* __restrict__ row_off, const int* __restrict__ csr_src,
    float* __restrict__ OUT)
{
  int node = blockIdx.x * 4 + (threadIdx.x >> 6);
  if (node >= NN) return;
  int lane = threadIdx.x & 63;
  int g = lane >> 4, l = lane & 15;
  bool h1 = (l & 8) != 0;
  float2 ar = ((const float2*)AR)[node];
  float m0 = lrelu(fdec(mAL[0]) + ar.x);
  float m1 = lrelu(fdec(mAL[1]) + ar.y);
  float ar_s = h1 ? ar.y : ar.x;
  float m_s  = h1 ? m1 : m0;
  int beg = row_off[node], end = row_off[node+1];
  float acc[8] = {};
  float s_acc = 0.f;
  for (int i = beg; i < end; i += 8) {
    int iA = i + g, iB = i + 4 + g;
    bool vA = iA < end, vB = iB < end;
    int eA = vA ? iA : beg;
    int eB = vB ? iB : beg;
    int sA = ntl(&csr_src[eA]);
    int sB = ntl(&csr_src[eB]);
    float2 alA = ((const float2*)AL)[sA];
    float2 alB = ((const float2*)AL)[sB];
    uint4 dA = *(const uint4*)(XLh + (size_t)sA*FD + 8*l);
    uint4 dB = *(const uint4*)(XLh + (size_t)sB*FD + 8*l);
    float wA = __expf(lrelu((h1 ? alA.y : alA.x) + ar_s) - m_s);
    float wB = __expf(lrelu((h1 ? alB.y : alB.x) + ar_s) - m_s);
    wA = vA ? wA : 0.f;
    wB = vB ? wB : 0.f;
    s_acc += wA + wB;
    const __half2* hA = (const __half2*)&dA;
    const __half2* hB = (const __half2*)&dB;
    #pragma unroll
    for (int q = 0; q < 4; ++q) {
      float2 fA = __half22float2(hA[q]);
      float2 fB = __half22float2(hB[q]);
      acc[2*q]   = fmaf(wA, fA.x, acc[2*q]);
      acc[2*q+1] = fmaf(wA, fA.y, acc[2*q+1]);
      acc[2*q]   = fmaf(wB, fB.x, acc[2*q]);
      acc[2*q+1] = fmaf(wB, fB.y, acc[2*q+1]);
    }
  }
  // reduce across the 4 edge-groups (lanes with equal l)
  #pragma unroll
  for (int off = 16; off < 64; off <<= 1) {
    s_acc += __shfl_xor(s_acc, off);
    #pragma unroll
    for (int q = 0; q < 8; ++q) acc[q] += __shfl_xor(acc[q], off);
  }
  if (g == 0) {
    float sinv = 1.f / (s_acc + 1e-16f);
    float4 o0, o1;
    o0.x = fmaxf(acc[0]*sinv, 0.f); o0.y = fmaxf(acc[1]*sinv, 0.f);
    o0.z = fmaxf(acc[2]*sinv, 0.f); o0.w = fmaxf(acc[3]*sinv, 0.f);
    o1.x = fmaxf(acc[4]*sinv, 0.f); o1.y = fmaxf(acc[5]*sinv, 0.f);
    o1.z = fmaxf(acc[6]*sinv, 0.f); o1.w = fmaxf(acc[7]*sinv, 0.f);
    *(float4*)&OUT[(size_t)node*FD + 8*l]     = o0;
    *(float4*)&OUT[(size_t)node*FD + 8*l + 4] = o1;
  }
}

// ---------------- post_mp (collapsed) + log_softmax ----------------
__global__ __launch_bounds__(256) void k_post(
    const float* __restrict__ H, const float* __restrict__ Wp, const float* __restrict__ bp,
    float* __restrict__ out)
{
  __shared__ float sW[FD*OUTD];
  int t = threadIdx.x;
  for (int i = t; i < FD*OUTD; i += 256) sW[i] = Wp[i];
  __syncthreads();
  int node = blockIdx.x * 4 + (t >> 6);
  if (node >= NN) return;
  int lane = t & 63;
  int col = (lane < OUTD) ? lane : (OUTD - 1);
  float acc = bp[col];
  const float* hbase = H + (size_t)node * FD;
  #pragma unroll 8
  for (int k4 = 0; k4 < FD/4; ++k4) {
    nfloat4 hv = ntl4(hbase + 4*k4);
    acc = fmaf(hv.x, sW[(k4*4+0)*OUTD + col], acc);
    acc = fmaf(hv.y, sW[(k4*4+1)*OUTD + col], acc);
    acc = fmaf(hv.z, sW[(k4*4+2)*OUTD + col], acc);
    acc = fmaf(hv.w, sW[(k4*4+3)*OUTD + col], acc);
  }
  float z = (lane < OUTD) ? acc : -INFINITY;
  float m = z;
  #pragma unroll
  for (int off = 1; off < 64; off <<= 1) m = fmaxf(m, __shfl_xor(m, off));
  float ex = (lane < OUTD) ? __expf(z - m) : 0.f;
  float s = ex;
  #pragma unroll
  for (int off = 1; off < 64; off <<= 1) s += __shfl_xor(s, off);
  float res = z - m - __logf(s);
  if (lane < OUTD) out[(size_t)node*OUTD + lane] = res;
}

// ---------------- launch ----------------
extern "C" void kernel_launch(void* const* d_in, const int* in_sizes, int n_in,
                              void* d_out, int out_size, void* d_ws, size_t ws_size,
                              hipStream_t stream)
{
  const float* x   = (const float*)d_in[0];
  const int*   ei  = (const int*)d_in[1];
  const float* Wl0 = (const float*)d_in[2];
  const float* bl0 = (const float*)d_in[3];
  const float* Wr0 = (const float*)d_in[4];
  const float* br0 = (const float*)d_in[5];
  const float* al0 = (const float*)d_in[6];
  const float* ar0 = (const float*)d_in[7];
  const float* Wl1 = (const float*)d_in[8];
  const float* bl1 = (const float*)d_in[9];
  const float* Wr1 = (const float*)d_in[10];
  const float* br1 = (const float*)d_in[11];
  const float* al1 = (const float*)d_in[12];
  const float* ar1 = (const float*)d_in[13];
  const float* Wm1 = (const float*)d_in[14];
  const float* bm1 = (const float*)d_in[15];
  const float* Wm2 = (const float*)d_in[16];
  const float* bm2 = (const float*)d_in[17];
  const int* srcA = ei;
  const int* dstA = ei + EE;

  char* w = (char*)d_ws;
  __half* XLh    = (__half*)w;  w += (size_t)NN*FD*2;    // 12.8 MB
  float* bufB    = (float*)w;  w += (size_t)NN*FD*4;     // 25.6 MB
  float* AL      = (float*)w;  w += (size_t)NN*2*4;
  float* AR      = (float*)w;  w += (size_t)NN*2*4;
  float* wrv0    = (float*)w;  w += 256*4;
  float* wrv1    = (float*)w;  w += 256*4;
  float* brd0    = (float*)w;  w += 16;
  float* brd1    = (float*)w;  w += 16;
  float* Wp      = (float*)w;  w += FD*OUTD*4;
  float* bp      = (float*)w;  w += 64*4;
  int* mAL       = (int*)w;    w += 4*4;
  int* cnt       = (int*)w;    w += (size_t)NN*4;
  int* cursor    = (int*)w;    w += (size_t)NN*4;        // adjacent to cnt: one memset
  int* row_off   = (int*)w;    w += (size_t)(NN+1)*4 + 12;
  int* partials  = (int*)w;    w += 256*4;
  int* poff      = (int*)w;    w += 256*4;
  int* csr_src   = (int*)w;    w += (size_t)EE*4;        // 6.4 MB

  hipMemsetAsync(cnt, 0, (size_t)NN*2*4, stream);

  k_precompute<<<23, 256, 0, stream>>>(Wr0, ar0, br0, Wr1, ar1, br1, Wm1, bm1, Wm2, bm2,
                                       wrv0, brd0, wrv1, brd1, Wp, bp, mAL);

  // CSR build (shared by both layers), XCD-partitioned
  k_hist<<<SCAT_BLOCKS, 256, 0, stream>>>(dstA, cnt);
  k_scan1<<<(NN+255)/256, 256, 0, stream>>>(cnt, row_off, partials);
  k_scan2<<<1, 256, 0, stream>>>(partials, poff);
  k_scan3<<<(NN+255)/256, 256, 0, stream>>>(row_off, poff);
  k_scatter<<<SCAT_BLOCKS, 256, 0, stream>>>(srcA, dstA, row_off, cursor, csr_src);

  // layer 0
  k_gemm_alpha<<<(NN+31)/32, 256, 0, stream>>>(x, Wl0, bl0, al0, wrv0, brd0, XLh, AL, AR);
  k_maxal<<<128, 256, 0, stream>>>(AL, mAL + 0);
  k_agg<<<(NN+3)/4, 256, 0, stream>>>(XLh, AL, AR, mAL + 0, row_off, csr_src, bufB);
  // layer 1
  k_gemm_alpha<<<(NN+31)/32, 256, 0, stream>>>(bufB, Wl1, bl1, al1, wrv1, brd1, XLh, AL, AR);
  k_maxal<<<128, 256, 0, stream>>>(AL, mAL + 2);
  k_agg<<<(NN+3)/4, 256, 0, stream>>>(XLh, AL, AR, mAL + 2, row_off, csr_src, bufB);
  // post_mp + log_softmax
  k_post<<<(NN+3)/4, 256, 0, stream>>>(bufB, Wp, bp, (float*)d_out);
}

// Round 6
// 336.280 us; speedup vs baseline: 1.3347x; 1.3347x over previous
//
#include <hip/hip_runtime.h>
#include <hip/hip_fp16.h>
#include <math.h>

#define NN   50000
#define EE   1600000
#define FD   128
#define OUTD 40
#define NEG  0.2f
#define NB   196           // ceil(NN/256) buckets of 256 nodes
#define ABLK 256           // pass-A blocks
#define ACH  (EE/ABLK)     // 6250 edges per pass-A block (exact)
#define BCAP 12288         // LDS staging capacity (mean 8163, +45 sigma)

__device__ __forceinline__ float lrelu(float v) { return v > 0.f ? v : NEG * v; }

__device__ __forceinline__ int fenc(float f) { int b = __float_as_int(f); return b < 0 ? (b ^ 0x7FFFFFFF) : b; }
__device__ __forceinline__ float fdec(int v) { v = v < 0 ? (v ^ 0x7FFFFFFF) : v; return __int_as_float(v); }

struct alignas(8) half4 { __half2 lo, hi; };

// ---------------- precompute collapsed weights ----------------
__global__ __launch_bounds__(256) void k_precompute(
    const float* __restrict__ Wr0, const float* __restrict__ ar0, const float* __restrict__ br0,
    const float* __restrict__ Wr1, const float* __restrict__ ar1, const float* __restrict__ br1,
    const float* __restrict__ Wm1, const float* __restrict__ bm1,
    const float* __restrict__ Wm2, const float* __restrict__ bm2,
    float* __restrict__ wrv0, float* __restrict__ brd0,
    float* __restrict__ wrv1, float* __restrict__ brd1,
    float* __restrict__ Wp, float* __restrict__ bp, int* __restrict__ mAL)
{
  int gid = blockIdx.x * 256 + threadIdx.x;
  if (gid < 256) {
    int k = gid >> 1, h = gid & 1;
    float s = 0.f;
    for (int c = 0; c < 64; ++c) s += Wr0[k*FD + h*64 + c] * ar0[h*64 + c];
    wrv0[k*2 + h] = s;
  } else if (gid < 512) {
    int idx = gid - 256; int k = idx >> 1, h = idx & 1;
    float s = 0.f;
    for (int c = 0; c < 64; ++c) s += Wr1[k*FD + h*64 + c] * ar1[h*64 + c];
    wrv1[k*2 + h] = s;
  } else if (gid < 512 + FD*OUTD) {
    int idx = gid - 512; int k = idx / OUTD, o = idx % OUTD;
    float s = 0.f;
    for (int j = 0; j < 64; ++j) s += Wm1[k*64 + j] * Wm2[j*OUTD + o];
    Wp[k*OUTD + o] = s;
  } else if (gid < 512 + FD*OUTD + OUTD) {
    int o = gid - (512 + FD*OUTD);
    float s = bm2[o];
    for (int j = 0; j < 64; ++j) s += bm1[j] * Wm2[j*OUTD + o];
    bp[o] = s;
  } else if (gid < 512 + FD*OUTD + OUTD + 4) {
    int idx = gid - (512 + FD*OUTD + OUTD);
    int l = idx >> 1, h = idx & 1;
    const float* br = l ? br1 : br0;
    const float* ar = l ? ar1 : ar0;
    float s = 0.f;
    for (int c = 0; c < 64; ++c) s += br[h*64 + c] * ar[h*64 + c];
    (l ? brd1 : brd0)[h] = s;
  } else if (gid < 512 + FD*OUTD + OUTD + 8) {
    mAL[gid - (512 + FD*OUTD + OUTD + 4)] = 0x80000000;
  }
}

// ---------------- fused GEMM + alpha_l + alpha_r; writes XL as f16 ----------------
__global__ __launch_bounds__(256) void k_gemm_alpha(
    const float* __restrict__ X, const float* __restrict__ Wl, const float* __restrict__ bl,
    const float* __restrict__ al, const float* __restrict__ wrv, const float* __restrict__ brd,
    __half* __restrict__ XLh, float* __restrict__ AL, float* __restrict__ AR)
{
  __shared__ float sW[FD*FD];
  __shared__ float sX[32*FD];
  int t = threadIdx.x;
  int base = blockIdx.x * 32;
  {
    const float4* W4 = (const float4*)Wl;
    float4* sW4 = (float4*)sW;
    #pragma unroll
    for (int i = 0; i < 16; ++i) sW4[t + i*256] = W4[t + i*256];
    int rows = NN - base; if (rows > 32) rows = 32;
    int nf4 = rows * 32;
    const float4* X4 = (const float4*)(X + (size_t)base * FD);
    float4* sX4 = (float4*)sX;
    #pragma unroll
    for (int i = 0; i < 4; ++i) {
      int idx = t + i*256;
      sX4[idx] = (idx < nf4) ? X4[idx] : make_float4(0.f,0.f,0.f,0.f);
    }
  }
  __syncthreads();
  int cg = t & 31, rg = t >> 5;
  int c0 = cg * 4;
  float acc[4][4] = {};
  #pragma unroll 4
  for (int k = 0; k < FD; ++k) {
    float4 wv = *(const float4*)&sW[k*FD + c0];
    #pragma unroll
    for (int r = 0; r < 4; ++r) {
      float xv = sX[(rg*4+r)*FD + k];
      acc[r][0] = fmaf(xv, wv.x, acc[r][0]);
      acc[r][1] = fmaf(xv, wv.y, acc[r][1]);
      acc[r][2] = fmaf(xv, wv.z, acc[r][2]);
      acc[r][3] = fmaf(xv, wv.w, acc[r][3]);
    }
  }
  float4 bias = *(const float4*)&bl[c0];
  int lane = t & 63;
  int head = cg >> 4;
  const float* alh = al + head*64 + (c0 & 63);
  float a0_0 = alh[0], a0_1 = alh[1], a0_2 = alh[2], a0_3 = alh[3];
  #pragma unroll
  for (int r = 0; r < 4; ++r) {
    int row = base + rg*4 + r;
    float4 o;
    o.x = acc[r][0] + bias.x; o.y = acc[r][1] + bias.y;
    o.z = acc[r][2] + bias.z; o.w = acc[r][3] + bias.w;
    if (row < NN) {
      half4 hv; hv.lo = __floats2half2_rn(o.x, o.y); hv.hi = __floats2half2_rn(o.z, o.w);
      *(half4*)&XLh[(size_t)row*FD + c0] = hv;
    }
    float av = o.x*a0_0 + o.y*a0_1 + o.z*a0_2 + o.w*a0_3;
    #pragma unroll
    for (int off = 1; off < 16; off <<= 1) av += __shfl_xor(av, off);
    if ((lane & 15) == 0 && row < NN) AL[(size_t)row*2 + head] = av;
    float p0 = 0.f, p1 = 0.f;
    #pragma unroll
    for (int j = 0; j < 4; ++j) {
      float xv = sX[(rg*4+r)*FD + c0 + j];
      p0 = fmaf(xv, wrv[(c0+j)*2 + 0], p0);
      p1 = fmaf(xv, wrv[(c0+j)*2 + 1], p1);
    }
    #pragma unroll
    for (int off = 1; off < 32; off <<= 1) { p0 += __shfl_xor(p0, off); p1 += __shfl_xor(p1, off); }
    if ((lane & 31) == 0 && row < NN) {
      AR[(size_t)row*2 + 0] = p0 + brd[0];
      AR[(size_t)row*2 + 1] = p1 + brd[1];
    }
  }
}

// ---------------- global max of AL per head ----------------
__global__ __launch_bounds__(256) void k_maxal(const float* __restrict__ AL, int* __restrict__ mAL) {
  float m0 = -INFINITY, m1 = -INFINITY;
  for (int i = blockIdx.x*256 + threadIdx.x; i < NN; i += gridDim.x*256) {
    float2 v = ((const float2*)AL)[i];
    m0 = fmaxf(m0, v.x); m1 = fmaxf(m1, v.y);
  }
  #pragma unroll
  for (int off = 1; off < 64; off <<= 1) {
    m0 = fmaxf(m0, __shfl_xor(m0, off));
    m1 = fmaxf(m1, __shfl_xor(m1, off));
  }
  if ((threadIdx.x & 63) == 0) {
    atomicMax(&mAL[0], fenc(m0));
    atomicMax(&mAL[1], fenc(m1));
  }
}

// ================= bucket CSR build =================
// Pass A1: per-bucket global counts (LDS-staged)
__global__ __launch_bounds__(256) void k_bhist(const int* __restrict__ dst, int* __restrict__ gbcnt) {
  __shared__ int hist[NB];
  int t = threadIdx.x;
  if (t < NB) hist[t] = 0;
  __syncthreads();
  int e0 = blockIdx.x * ACH;
  for (int e = e0 + t; e < e0 + ACH; e += 256)
    atomicAdd(&hist[dst[e] >> 8], 1);
  __syncthreads();
  if (t < NB) atomicAdd(&gbcnt[t], hist[t]);
}

// Pass A2: exclusive scan of 196 bucket counts -> boff; init gcur; row_off tail
__global__ __launch_bounds__(256) void k_bscan(const int* __restrict__ gbcnt,
                                               int* __restrict__ boff, int* __restrict__ gcur,
                                               int* __restrict__ row_off) {
  __shared__ int tmp[256];
  int t = threadIdx.x;
  int v = (t < NB) ? gbcnt[t] : 0;
  tmp[t] = v;
  __syncthreads();
  #pragma unroll
  for (int off = 1; off < 256; off <<= 1) {
    int u = (t >= off) ? tmp[t - off] : 0;
    __syncthreads();
    tmp[t] += u;
    __syncthreads();
  }
  int excl = tmp[t] - v;
  if (t < NB) { boff[t] = excl; gcur[t] = excl; }
  if (t == 0) { boff[NB] = EE; row_off[NN] = EE; }
}

// Pass A3: chunk-grab placement of (dstLow,src) pairs, bucket-grouped, ~128B runs
__global__ __launch_bounds__(256) void k_bplace(const int* __restrict__ src, const int* __restrict__ dst,
    int* __restrict__ gcur, unsigned int* __restrict__ pair_buf) {
  __shared__ int hist[NB];
  __shared__ int base_l[NB];
  __shared__ int lcur[NB];
  int t = threadIdx.x;
  if (t < NB) { hist[t] = 0; lcur[t] = 0; }
  __syncthreads();
  int e0 = blockIdx.x * ACH;
  for (int e = e0 + t; e < e0 + ACH; e += 256)
    atomicAdd(&hist[dst[e] >> 8], 1);
  __syncthreads();
  if (t < NB) base_l[t] = atomicAdd(&gcur[t], hist[t]);
  __syncthreads();
  for (int e = e0 + t; e < e0 + ACH; e += 256) {
    int d = dst[e];
    int b = d >> 8;
    int p = base_l[b] + atomicAdd(&lcur[b], 1);
    pair_buf[p] = (unsigned int)src[e] | ((unsigned int)(d & 255) << 16);
  }
}

// Pass B: per-bucket local reorder in LDS -> node-grouped u16 csr + row_off
__global__ __launch_bounds__(256) void k_bfinal(const unsigned int* __restrict__ pair_buf,
    const int* __restrict__ boff, int* __restrict__ row_off,
    unsigned short* __restrict__ csr16) {
  __shared__ int hist[256];
  __shared__ int rel[256];
  __shared__ unsigned short stage[BCAP];
  int g = blockIdx.x;
  int t = threadIdx.x;
  int e0 = boff[g], e1 = boff[g+1];
  int cnt = e1 - e0;
  hist[t] = 0;
  __syncthreads();
  for (int i = e0 + t; i < e1; i += 256)
    atomicAdd(&hist[pair_buf[i] >> 16], 1);
  __syncthreads();
  // exclusive scan of hist -> rel
  int v = hist[t];
  rel[t] = v;
  __syncthreads();
  #pragma unroll
  for (int off = 1; off < 256; off <<= 1) {
    int u = (t >= off) ? rel[t - off] : 0;
    __syncthreads();
    rel[t] += u;
    __syncthreads();
  }
  int excl = rel[t] - v;
  __syncthreads();
  rel[t] = excl;
  int node = g*256 + t;
  if (node < NN) row_off[node] = e0 + excl;
  hist[t] = 0;  // reuse as cursors
  __syncthreads();
  bool staged = (cnt <= BCAP);
  for (int i = e0 + t; i < e1; i += 256) {
    unsigned int p = pair_buf[i];
    int j = p >> 16;
    int l = atomicAdd(&hist[j], 1);
    if (staged) stage[rel[j] + l] = (unsigned short)(p & 0xFFFF);
    else        csr16[e0 + rel[j] + l] = (unsigned short)(p & 0xFFFF);
  }
  __syncthreads();
  if (staged)
    for (int i = t; i < cnt; i += 256) csr16[e0 + i] = stage[i];
}

// ---------------- fused attention + aggregation ----------------
// wave per node; 4 edge-groups x 16 lanes; lane l covers dims [8l, 8l+8) (head = l>>3)
__global__ __launch_bounds__(256) void k_agg(
    const __half* __restrict__ XLh, const float* __restrict__ AL,
    const float* __restrict__ AR, const int* __restrict__ mAL,
    const int* __restrict__ row_off, const unsigned short* __restrict__ csr16,
    float* __restrict__ OUT)
{
  int node = blockIdx.x * 4 + (threadIdx.x >> 6);
  if (node >= NN) return;
  int lane = threadIdx.x & 63;
  int g = lane >> 4, l = lane & 15;
  bool h1 = (l & 8) != 0;
  float2 ar = ((const float2*)AR)[node];
  float m0 = lrelu(fdec(mAL[0]) + ar.x);
  float m1 = lrelu(fdec(mAL[1]) + ar.y);
  float ar_s = h1 ? ar.y : ar.x;
  float m_s  = h1 ? m1 : m0;
  int beg = row_off[node], end = row_off[node+1];
  float acc[8] = {};
  float s_acc = 0.f;
  for (int i = beg; i < end; i += 8) {
    int iA = i + g, iB = i + 4 + g;
    bool vA = iA < end, vB = iB < end;
    int eA = vA ? iA : beg;
    int eB = vB ? iB : beg;
    int sA = csr16[eA];
    int sB = csr16[eB];
    float2 alA = ((const float2*)AL)[sA];
    float2 alB = ((const float2*)AL)[sB];
    uint4 dA = *(const uint4*)(XLh + (size_t)sA*FD + 8*l);
    uint4 dB = *(const uint4*)(XLh + (size_t)sB*FD + 8*l);
    float wA = __expf(lrelu((h1 ? alA.y : alA.x) + ar_s) - m_s);
    float wB = __expf(lrelu((h1 ? alB.y : alB.x) + ar_s) - m_s);
    wA = vA ? wA : 0.f;
    wB = vB ? wB : 0.f;
    s_acc += wA + wB;
    const __half2* hA = (const __half2*)&dA;
    const __half2* hB = (const __half2*)&dB;
    #pragma unroll
    for (int q = 0; q < 4; ++q) {
      float2 fA = __half22float2(hA[q]);
      float2 fB = __half22float2(hB[q]);
      acc[2*q]   = fmaf(wA, fA.x, acc[2*q]);
      acc[2*q+1] = fmaf(wA, fA.y, acc[2*q+1]);
      acc[2*q]   = fmaf(wB, fB.x, acc[2*q]);
      acc[2*q+1] = fmaf(wB, fB.y, acc[2*q+1]);
    }
  }
  // reduce across the 4 edge-groups (lanes with equal l)
  #pragma unroll
  for (int off = 16; off < 64; off <<= 1) {
    s_acc += __shfl_xor(s_acc, off);
    #pragma unroll
    for (int q = 0; q < 8; ++q) acc[q] += __shfl_xor(acc[q], off);
  }
  if (g == 0) {
    float sinv = 1.f / (s_acc + 1e-16f);
    float4 o0, o1;
    o0.x = fmaxf(acc[0]*sinv, 0.f); o0.y = fmaxf(acc[1]*sinv, 0.f);
    o0.z = fmaxf(acc[2]*sinv, 0.f); o0.w = fmaxf(acc[3]*sinv, 0.f);
    o1.x = fmaxf(acc[4]*sinv, 0.f); o1.y = fmaxf(acc[5]*sinv, 0.f);
    o1.z = fmaxf(acc[6]*sinv, 0.f); o1.w = fmaxf(acc[7]*sinv, 0.f);
    *(float4*)&OUT[(size_t)node*FD + 8*l]     = o0;
    *(float4*)&OUT[(size_t)node*FD + 8*l + 4] = o1;
  }
}

// ---------------- post_mp (collapsed) + log_softmax ----------------
__global__ __launch_bounds__(256) void k_post(
    const float* __restrict__ H, const float* __restrict__ Wp, const float* __restrict__ bp,
    float* __restrict__ out)
{
  __shared__ float sW[FD*OUTD];
  int t = threadIdx.x;
  for (int i = t; i < FD*OUTD; i += 256) sW[i] = Wp[i];
  __syncthreads();
  int node = blockIdx.x * 4 + (t >> 6);
  if (node >= NN) return;
  int lane = t & 63;
  int col = (lane < OUTD) ? lane : (OUTD - 1);
  float acc = bp[col];
  const float4* h4 = (const float4*)(H + (size_t)node * FD);
  #pragma unroll 8
  for (int k4 = 0; k4 < FD/4; ++k4) {
    float4 hv = h4[k4];
    acc = fmaf(hv.x, sW[(k4*4+0)*OUTD + col], acc);
    acc = fmaf(hv.y, sW[(k4*4+1)*OUTD + col], acc);
    acc = fmaf(hv.z, sW[(k4*4+2)*OUTD + col], acc);
    acc = fmaf(hv.w, sW[(k4*4+3)*OUTD + col], acc);
  }
  float z = (lane < OUTD) ? acc : -INFINITY;
  float m = z;
  #pragma unroll
  for (int off = 1; off < 64; off <<= 1) m = fmaxf(m, __shfl_xor(m, off));
  float ex = (lane < OUTD) ? __expf(z - m) : 0.f;
  float s = ex;
  #pragma unroll
  for (int off = 1; off < 64; off <<= 1) s += __shfl_xor(s, off);
  float res = z - m - __logf(s);
  if (lane < OUTD) out[(size_t)node*OUTD + lane] = res;
}

// ---------------- launch ----------------
extern "C" void kernel_launch(void* const* d_in, const int* in_sizes, int n_in,
                              void* d_out, int out_size, void* d_ws, size_t ws_size,
                              hipStream_t stream)
{
  const float* x   = (const float*)d_in[0];
  const int*   ei  = (const int*)d_in[1];
  const float* Wl0 = (const float*)d_in[2];
  const float* bl0 = (const float*)d_in[3];
  const float* Wr0 = (const float*)d_in[4];
  const float* br0 = (const float*)d_in[5];
  const float* al0 = (const float*)d_in[6];
  const float* ar0 = (const float*)d_in[7];
  const float* Wl1 = (const float*)d_in[8];
  const float* bl1 = (const float*)d_in[9];
  const float* Wr1 = (const float*)d_in[10];
  const float* br1 = (const float*)d_in[11];
  const float* al1 = (const float*)d_in[12];
  const float* ar1 = (const float*)d_in[13];
  const float* Wm1 = (const float*)d_in[14];
  const float* bm1 = (const float*)d_in[15];
  const float* Wm2 = (const float*)d_in[16];
  const float* bm2 = (const float*)d_in[17];
  const int* srcA = ei;
  const int* dstA = ei + EE;

  char* w = (char*)d_ws;
  __half* XLh    = (__half*)w;  w += (size_t)NN*FD*2;    // 12.8 MB
  float* bufB    = (float*)w;  w += (size_t)NN*FD*4;     // 25.6 MB
  float* AL      = (float*)w;  w += (size_t)NN*2*4;
  float* AR      = (float*)w;  w += (size_t)NN*2*4;
  float* wrv0    = (float*)w;  w += 256*4;
  float* wrv1    = (float*)w;  w += 256*4;
  float* brd0    = (float*)w;  w += 16;
  float* brd1    = (float*)w;  w += 16;
  float* Wp      = (float*)w;  w += FD*OUTD*4;
  float* bp      = (float*)w;  w += 64*4;
  int* mAL       = (int*)w;    w += 4*4;
  int* gbcnt     = (int*)w;    w += NB*4;
  int* gcur      = (int*)w;    w += NB*4;
  int* boff      = (int*)w;    w += (NB+1)*4 + 12;
  int* row_off   = (int*)w;    w += (size_t)(NN+1)*4 + 12;
  unsigned int* pair_buf = (unsigned int*)w; w += (size_t)EE*4;  // 6.4 MB
  unsigned short* csr16  = (unsigned short*)w; w += (size_t)EE*2; // 3.2 MB

  hipMemsetAsync(gbcnt, 0, NB*4, stream);

  k_precompute<<<23, 256, 0, stream>>>(Wr0, ar0, br0, Wr1, ar1, br1, Wm1, bm1, Wm2, bm2,
                                       wrv0, brd0, wrv1, brd1, Wp, bp, mAL);

  // CSR build (shared by both layers): bucket two-phase, LDS-confined randomness
  k_bhist<<<ABLK, 256, 0, stream>>>(dstA, gbcnt);
  k_bscan<<<1, 256, 0, stream>>>(gbcnt, boff, gcur, row_off);
  k_bplace<<<ABLK, 256, 0, stream>>>(srcA, dstA, gcur, pair_buf);
  k_bfinal<<<NB, 256, 0, stream>>>(pair_buf, boff, row_off, csr16);

  // layer 0
  k_gemm_alpha<<<(NN+31)/32, 256, 0, stream>>>(x, Wl0, bl0, al0, wrv0, brd0, XLh, AL, AR);
  k_maxal<<<128, 256, 0, stream>>>(AL, mAL + 0);
  k_agg<<<(NN+3)/4, 256, 0, stream>>>(XLh, AL, AR, mAL + 0, row_off, csr16, bufB);
  // layer 1
  k_gemm_alpha<<<(NN+31)/32, 256, 0, stream>>>(bufB, Wl1, bl1, al1, wrv1, brd1, XLh, AL, AR);
  k_maxal<<<128, 256, 0, stream>>>(AL, mAL + 2);
  k_agg<<<(NN+3)/4, 256, 0, stream>>>(XLh, AL, AR, mAL + 2, row_off, csr16, bufB);
  // post_mp + log_softmax
  k_post<<<(NN+3)/4, 256, 0, stream>>>(bufB, Wp, bp, (float*)d_out);
}